// Round 5
// baseline (469.311 us; speedup 1.0000x reference)
//
#include <hip/hip_runtime.h>

// Problem constants: B=2, S=2048, D=1024, H=16, HD=64
#define S_LEN 2048
#define NH 16
#define HD 64
#define DMODEL 1024

typedef __bf16 bf16x8 __attribute__((ext_vector_type(8)));
typedef float floatx4 __attribute__((ext_vector_type(4)));
typedef short short8 __attribute__((ext_vector_type(8)));

__device__ inline unsigned short f2bf(float f) {
    union { float f; unsigned u; } v; v.f = f;
    unsigned u = v.u;
    unsigned r = (u + 0x7FFFu + ((u >> 16) & 1u)) >> 16;  // RNE
    return (unsigned short)r;
}

__device__ __forceinline__ void gload_lds16(const void* g, void* l) {
    __builtin_amdgcn_global_load_lds(
        (const __attribute__((address_space(1))) unsigned int*)g,
        (__attribute__((address_space(3))) unsigned int*)l, 16, 0, 0);
}

// ---------------------------------------------------------------------------
// K0: convert x, w_qkv, w_proj (fp32 row-major, K=1024) to bf16 in blocked
// layout [kchunk(128)][row][8].  Reads coalesced; writes 16B scattered
// (write-combine absorbs).  1,048,576 threads.
// ---------------------------------------------------------------------------
__global__ __launch_bounds__(256) void convert_kernel(
    const float* __restrict__ x, const float* __restrict__ wq,
    const float* __restrict__ wp,
    unsigned short* __restrict__ xb, unsigned short* __restrict__ wqb,
    unsigned short* __restrict__ wpb)
{
    const int f = blockIdx.x * 256 + threadIdx.x;
    const float* src; unsigned short* dst; int NR, g;
    if (f < 524288)      { src = x;  dst = xb;  NR = 4096; g = f; }
    else if (f < 917504) { src = wq; dst = wqb; NR = 3072; g = f - 524288; }
    else                 { src = wp; dst = wpb; NR = 1024; g = f - 917504; }
    const int kc = g & 127, row = g >> 7;
    const float* p = src + (size_t)row * 1024 + kc * 8;
    float4 a = *(const float4*)p;
    float4 b = *(const float4*)(p + 4);
    short8 o;
    o[0]=(short)f2bf(a.x); o[1]=(short)f2bf(a.y); o[2]=(short)f2bf(a.z); o[3]=(short)f2bf(a.w);
    o[4]=(short)f2bf(b.x); o[5]=(short)f2bf(b.y); o[6]=(short)f2bf(b.z); o[7]=(short)f2bf(b.w);
    *(short8*)&dst[((size_t)kc * NR + row) * 8] = o;
}

// ---------------------------------------------------------------------------
// K1: qkv = x @ w_qkv^T + b_qkv (bf16 blocked inputs), fused RoPE + scatter.
// m97 structure: 128x128 tile, BK=32, 4 waves 2x2, global_load_lds staging,
// 16 MFMA : 8 ds_read_b128 : 4 gload per K-step, 2 barriers.
//  q -> [bh][s][hd] row-major, pre-scaled by 0.125
//  k -> blocked [bh][hdblk(8)][s(2048)][8]
//  v -> blocked [bh][sblk(256)][hd(64)][8]
// ---------------------------------------------------------------------------
__global__ __launch_bounds__(256) void qkv_rope_kernel(
    const unsigned short* __restrict__ xb, const unsigned short* __restrict__ wqb,
    const float* __restrict__ bias, const float* __restrict__ freqs,
    unsigned short* __restrict__ qb, unsigned short* __restrict__ kb,
    unsigned short* __restrict__ vb)
{
    __shared__ __align__(16) unsigned short As[4096];  // [kchunk(4)][row(128)][8]
    __shared__ __align__(16) unsigned short Bs[4096];

    const int t = threadIdx.x;
    const int wv = t >> 6, lane = t & 63, quad = lane >> 4, l16 = lane & 15;
    const int mbase = (blockIdx.x / 24) * 128;
    const int nbase = (blockIdx.x % 24) * 128;
    const int wm = wv >> 1, wn = wv & 1;

    floatx4 acc[4][4];
    for (int i = 0; i < 4; i++)
        for (int j = 0; j < 4; j++)
            for (int r = 0; r < 4; r++) acc[i][j][r] = 0.f;

    for (int kc0 = 0; kc0 < 128; kc0 += 4) {
        __syncthreads();   // prev iter's frag reads done
        const unsigned short* ga = xb + ((size_t)(kc0 + wv) * 4096 + mbase + lane) * 8;
        gload_lds16(ga,          &As[wv * 1024 + lane * 8]);
        gload_lds16(ga + 64 * 8, &As[wv * 1024 + (64 + lane) * 8]);
        const unsigned short* gb = wqb + ((size_t)(kc0 + wv) * 3072 + nbase + lane) * 8;
        gload_lds16(gb,          &Bs[wv * 1024 + lane * 8]);
        gload_lds16(gb + 64 * 8, &Bs[wv * 1024 + (64 + lane) * 8]);
        __syncthreads();   // staging visible

        bf16x8 af[4], bfr[4];
        #pragma unroll
        for (int mf = 0; mf < 4; mf++)
            af[mf] = *(const bf16x8*)&As[quad * 1024 + (wm * 64 + mf * 16 + l16) * 8];
        #pragma unroll
        for (int nf = 0; nf < 4; nf++)
            bfr[nf] = *(const bf16x8*)&Bs[quad * 1024 + (wn * 64 + nf * 16 + l16) * 8];
        #pragma unroll
        for (int mf = 0; mf < 4; mf++)
            #pragma unroll
            for (int nf = 0; nf < 4; nf++)
                acc[mf][nf] = __builtin_amdgcn_mfma_f32_16x16x32_bf16(af[mf], bfr[nf], acc[mf][nf], 0, 0, 0);
    }

    // ---- epilogue: wave quadrant = 64m x 64n; 64-col quadrant = one head
    const int nq = nbase + wn * 64;          // multiple of 64
    const int part = nq >> 10;               // 0=q 1=k 2=v (wave-uniform)
    const int h    = (nq & 1023) >> 6;
    const int mq   = mbase + wm * 64;
    const int bidx = mq >> 11;
    const int s0   = mq & 2047;
    const size_t bh = (size_t)bidx * NH + h;

    if (part == 2) {
        #pragma unroll
        for (int mf = 0; mf < 4; mf++) {
            const int s = s0 + mf * 16 + quad * 4;
            const int sblk = s >> 3;
            const int off  = (quad & 1) * 4;
            #pragma unroll
            for (int nf = 0; nf < 4; nf++) {
                const int hd = nf * 16 + l16;
                const float bvv = bias[nq + hd];
                union { unsigned short s4[4]; uint2 u; } pk;
                #pragma unroll
                for (int r = 0; r < 4; r++) pk.s4[r] = f2bf(acc[mf][nf][r] + bvv);
                *(uint2*)&vb[(((bh * 256) + sblk) * 64 + hd) * 8 + off] = pk.u;
            }
        }
    } else {
        #pragma unroll
        for (int nf = 0; nf < 4; nf++) {
            const int hd = nf * 16 + l16;
            const float bvv = bias[nq + hd];
            const int i = hd >> 1;
            #pragma unroll
            for (int mf = 0; mf < 4; mf++) {
                #pragma unroll
                for (int r = 0; r < 4; r++) {
                    const int s = s0 + mf * 16 + quad * 4 + r;
                    float val = acc[mf][nf][r] + bvv;
                    float other = __shfl_xor(val, 1, 64);   // RoPE pair = adjacent hd
                    const float f = freqs[s * 32 + i];
                    const float cc = cosf(f), sn = sinf(f);
                    float outv;
                    if ((hd & 1) == 0) outv = val * cc - other * sn;
                    else               outv = other * sn + val * cc;
                    if (part == 0) {
                        outv *= 0.125f;                     // fold 1/sqrt(HD)
                        qb[(bh * S_LEN + s) * HD + hd] = f2bf(outv);
                    } else {
                        kb[((bh * 8 + (hd >> 3)) * (size_t)S_LEN + s) * 8 + (hd & 7)] = f2bf(outv);
                    }
                }
            }
        }
    }
}

// ---------------------------------------------------------------------------
// K2: causal flash attention (R4 structure, unchanged except blocked ao).
// No-max softmax; transposed QK; grid 1024.
// ao -> blocked [kchunk(128)][row(4096)][8] for proj staging.
// ---------------------------------------------------------------------------
__global__ __launch_bounds__(256, 4) void attn_kernel(
    const unsigned short* __restrict__ qb, const unsigned short* __restrict__ kb,
    const unsigned short* __restrict__ vbk, unsigned short* __restrict__ aob)
{
    __shared__ __align__(16) unsigned short Ks[8 * 512];
    __shared__ __align__(16) unsigned short Vt[8 * 512];
    __shared__ __align__(16) unsigned short Pw[4][16 * 72];

    const int t = threadIdx.x;
    const int wv = t >> 6, lane = t & 63, quad = lane >> 4, l16 = lane & 15;
    const int qt   = blockIdx.x >> 5;
    const int bhid = blockIdx.x & 31;
    const int h = bhid & 15, b = bhid >> 4;
    const size_t bh = (size_t)b * NH + h;
    const unsigned short* qg  = qb + bh * S_LEN * HD;
    const unsigned short* kgB = kb + bh * 8 * S_LEN * 8;
    const unsigned short* vgB = vbk + bh * 256 * 64 * 8;

    bf16x8 qf[2];
    {
        const unsigned short* q0 = qg + (size_t)(qt * 64 + wv * 16 + l16) * HD;
        qf[0] = *(const bf16x8*)&q0[quad * 8];
        qf[1] = *(const bf16x8*)&q0[32 + quad * 8];
    }

    bf16x8 ones;
    {
        union { short8 s; bf16x8 v; } o;
        for (int j = 0; j < 8; j++) o.s[j] = 0x3F80;
        ones = o.v;
    }

    floatx4 lfr = {0.f, 0.f, 0.f, 0.f};
    floatx4 Ofr[4];
    for (int nt = 0; nt < 4; nt++)
        for (int r = 0; r < 4; r++) Ofr[nt][r] = 0.f;

    const int ntiles = qt + 1;

    for (int kt = 0; kt < ntiles; kt++) {
        const int kbase = kt * 64;
        {
            const unsigned short* g0 = kgB + ((size_t)(2 * wv) * S_LEN + kbase + lane) * 8;
            gload_lds16(g0,             &Ks[(2 * wv) * 512]);
            gload_lds16(g0 + S_LEN * 8, &Ks[(2 * wv + 1) * 512]);
            const unsigned short* g1 = vgB + ((size_t)((kbase >> 3) + 2 * wv) * 64 + lane) * 8;
            gload_lds16(g1,          &Vt[(2 * wv) * 512]);
            gload_lds16(g1 + 64 * 8, &Vt[(2 * wv + 1) * 512]);
        }
        __syncthreads();

        float pex[4][4];
        #pragma unroll
        for (int sub = 0; sub < 4; sub++) {
            bf16x8 kf0 = *(const bf16x8*)&Ks[(0 * 4 + quad) * 512 + (sub * 16 + l16) * 8];
            bf16x8 kf1 = *(const bf16x8*)&Ks[(1 * 4 + quad) * 512 + (sub * 16 + l16) * 8];
            floatx4 sacc = {0.f, 0.f, 0.f, 0.f};
            sacc = __builtin_amdgcn_mfma_f32_16x16x32_bf16(kf0, qf[0], sacc, 0, 0, 0);
            sacc = __builtin_amdgcn_mfma_f32_16x16x32_bf16(kf1, qf[1], sacc, 0, 0, 0);
            #pragma unroll
            for (int r = 0; r < 4; r++) pex[sub][r] = sacc[r];
        }
        if (kt == qt) {
            const int q = qt * 64 + wv * 16 + l16;
            #pragma unroll
            for (int sub = 0; sub < 4; sub++)
                #pragma unroll
                for (int r = 0; r < 4; r++) {
                    const int key = kbase + sub * 16 + quad * 4 + r;
                    if (key > q) pex[sub][r] = -1e30f;
                }
        }
        #pragma unroll
        for (int sub = 0; sub < 4; sub++) {
            union { unsigned short s[4]; uint2 u; } pk;
            #pragma unroll
            for (int r = 0; r < 4; r++) pk.s[r] = f2bf(__expf(pex[sub][r]));
            *(uint2*)&Pw[wv][l16 * 72 + sub * 16 + quad * 4] = pk.u;
        }
        bf16x8 pf0 = *(const bf16x8*)&Pw[wv][l16 * 72 + quad * 8];
        bf16x8 pf1 = *(const bf16x8*)&Pw[wv][l16 * 72 + 32 + quad * 8];
        lfr = __builtin_amdgcn_mfma_f32_16x16x32_bf16(ones, pf0, lfr, 0, 0, 0);
        lfr = __builtin_amdgcn_mfma_f32_16x16x32_bf16(ones, pf1, lfr, 0, 0, 0);
        #pragma unroll
        for (int nt = 0; nt < 4; nt++) {
            bf16x8 v0 = *(const bf16x8*)&Vt[(0 * 4 + quad) * 512 + (nt * 16 + l16) * 8];
            bf16x8 v1 = *(const bf16x8*)&Vt[(1 * 4 + quad) * 512 + (nt * 16 + l16) * 8];
            Ofr[nt] = __builtin_amdgcn_mfma_f32_16x16x32_bf16(pf0, v0, Ofr[nt], 0, 0, 0);
            Ofr[nt] = __builtin_amdgcn_mfma_f32_16x16x32_bf16(pf1, v1, Ofr[nt], 0, 0, 0);
        }
        __syncthreads();
    }

    float linv[4];
    #pragma unroll
    for (int r = 0; r < 4; r++) {
        float lq = __shfl(lfr[0], (lane & 48) | (quad * 4 + r), 64);
        linv[r] = 1.f / lq;
    }
    #pragma unroll
    for (int nt = 0; nt < 4; nt++) {
        const int kchunk = h * 8 + nt * 2 + (l16 >> 3);
        const int pos = l16 & 7;
        #pragma unroll
        for (int r = 0; r < 4; r++) {
            const int row = b * S_LEN + qt * 64 + wv * 16 + quad * 4 + r;
            aob[((size_t)kchunk * 4096 + row) * 8 + pos] = f2bf(Ofr[nt][r] * linv[r]);
        }
    }
}

// ---------------------------------------------------------------------------
// K3: out = ao @ w_proj^T + b_proj (blocked bf16 inputs), m97 structure.
// M=4096, N=1024, K=1024. Grid 256. fp32 out.
// ---------------------------------------------------------------------------
__global__ __launch_bounds__(256) void proj_kernel(
    const unsigned short* __restrict__ aob, const unsigned short* __restrict__ wpb,
    const float* __restrict__ bias, float* __restrict__ out)
{
    __shared__ __align__(16) unsigned short As[4096];
    __shared__ __align__(16) unsigned short Bs[4096];

    const int t = threadIdx.x;
    const int wv = t >> 6, lane = t & 63, quad = lane >> 4, l16 = lane & 15;
    const int mbase = (blockIdx.x >> 3) * 128;
    const int nbase = (blockIdx.x & 7) * 128;
    const int wm = wv >> 1, wn = wv & 1;

    floatx4 acc[4][4];
    for (int i = 0; i < 4; i++)
        for (int j = 0; j < 4; j++)
            for (int r = 0; r < 4; r++) acc[i][j][r] = 0.f;

    for (int kc0 = 0; kc0 < 128; kc0 += 4) {
        __syncthreads();
        const unsigned short* ga = aob + ((size_t)(kc0 + wv) * 4096 + mbase + lane) * 8;
        gload_lds16(ga,          &As[wv * 1024 + lane * 8]);
        gload_lds16(ga + 64 * 8, &As[wv * 1024 + (64 + lane) * 8]);
        const unsigned short* gb = wpb + ((size_t)(kc0 + wv) * 1024 + nbase + lane) * 8;
        gload_lds16(gb,          &Bs[wv * 1024 + lane * 8]);
        gload_lds16(gb + 64 * 8, &Bs[wv * 1024 + (64 + lane) * 8]);
        __syncthreads();

        bf16x8 af[4], bfr[4];
        #pragma unroll
        for (int mf = 0; mf < 4; mf++)
            af[mf] = *(const bf16x8*)&As[quad * 1024 + (wm * 64 + mf * 16 + l16) * 8];
        #pragma unroll
        for (int nf = 0; nf < 4; nf++)
            bfr[nf] = *(const bf16x8*)&Bs[quad * 1024 + (wn * 64 + nf * 16 + l16) * 8];
        #pragma unroll
        for (int mf = 0; mf < 4; mf++)
            #pragma unroll
            for (int nf = 0; nf < 4; nf++)
                acc[mf][nf] = __builtin_amdgcn_mfma_f32_16x16x32_bf16(af[mf], bfr[nf], acc[mf][nf], 0, 0, 0);
    }

    #pragma unroll
    for (int nf = 0; nf < 4; nf++) {
        const int n = nbase + wn * 64 + nf * 16 + l16;
        const float bvv = bias[n];
        #pragma unroll
        for (int mf = 0; mf < 4; mf++)
            #pragma unroll
            for (int r = 0; r < 4; r++) {
                const int m = mbase + wm * 64 + mf * 16 + quad * 4 + r;
                out[(size_t)m * DMODEL + n] = acc[mf][nf][r] + bvv;
            }
    }
}

extern "C" void kernel_launch(void* const* d_in, const int* in_sizes, int n_in,
                              void* d_out, int out_size, void* d_ws, size_t ws_size,
                              hipStream_t stream) {
    const float* x      = (const float*)d_in[0];
    const float* freqs  = (const float*)d_in[2];
    const float* w_qkv  = (const float*)d_in[3];
    const float* b_qkv  = (const float*)d_in[4];
    const float* w_proj = (const float*)d_in[5];
    const float* b_proj = (const float*)d_in[6];
    float* out = (float*)d_out;

    unsigned short* ws = (unsigned short*)d_ws;
    unsigned short* xb  = ws;                    // 4M shorts; aliased as aob later
    unsigned short* wqb = ws + 4194304;          // 3M
    unsigned short* wpb = ws + 7340032;          // 1M
    unsigned short* qb  = ws + 8388608;          // 4M
    unsigned short* kb  = ws + 12582912;         // 4M
    unsigned short* vb  = ws + 16777216;         // 4M
    unsigned short* aob = xb;                    // xb dead after qkv kernel

    convert_kernel<<<4096, 256, 0, stream>>>(x, w_qkv, w_proj, xb, wqb, wpb);
    qkv_rope_kernel<<<768, 256, 0, stream>>>(xb, wqb, b_qkv, freqs, qb, kb, vb);
    attn_kernel<<<1024, 256, 0, stream>>>(qb, kb, vb, aob);
    proj_kernel<<<256, 256, 0, stream>>>(aob, wpb, b_proj, out);
}

// Round 6
// 267.723 us; speedup vs baseline: 1.7530x; 1.7530x over previous
//
#include <hip/hip_runtime.h>

// Problem constants: B=2, S=2048, D=1024, H=16, HD=64
#define S_LEN 2048
#define NH 16
#define HD 64
#define DMODEL 1024

typedef __bf16 bf16x8 __attribute__((ext_vector_type(8)));
typedef float floatx4 __attribute__((ext_vector_type(4)));
typedef short short8 __attribute__((ext_vector_type(8)));

__device__ inline unsigned short f2bf(float f) {
    union { float f; unsigned u; } v; v.f = f;
    unsigned u = v.u;
    unsigned r = (u + 0x7FFFu + ((u >> 16) & 1u)) >> 16;  // RNE
    return (unsigned short)r;
}

// pack two fp32 -> bf16x2 by truncation: one v_perm_b32.
// sel 0x07060302: D = [lo.b2, lo.b3, hi.b2, hi.b3]
__device__ __forceinline__ unsigned pkhi(float lo, float hi) {
    union { float f; unsigned u; } a, b;
    a.f = lo; b.f = hi;
    return __builtin_amdgcn_perm(b.u, a.u, 0x07060302u);
}

__device__ __forceinline__ void gload_lds16(const void* g, void* l) {
    __builtin_amdgcn_global_load_lds(
        (const __attribute__((address_space(1))) unsigned int*)g,
        (__attribute__((address_space(3))) unsigned int*)l, 16, 0, 0);
}

// ---------------------------------------------------------------------------
// K1: qkv = x @ w_qkv^T + b_qkv, fused RoPE + scatter. (R4 structure; staging
// conversion via v_perm truncation instead of scalar RNE — VALU cut ~6x)
//  q -> [bh][s][hd] row-major, PRE-SCALED by 1/sqrt(HD)=0.125 (exact)
//  k -> blocked [bh][hdblk(8)][s(2048)][8]   (RoPE applied)
//  v -> blocked [bh][sblk(256)][hd(64)][8]   (transposed via LDS tile)
// ---------------------------------------------------------------------------
__global__ __launch_bounds__(256) void qkv_rope_kernel(
    const float* __restrict__ x, const float* __restrict__ w,
    const float* __restrict__ bias, const float* __restrict__ freqs,
    unsigned short* __restrict__ qb, unsigned short* __restrict__ kb,
    unsigned short* __restrict__ vb)
{
    __shared__ __align__(16) unsigned short smem[5120];  // As(2560) + Bs(2560)
    unsigned short* As = smem;
    unsigned short* Bs = smem + 2560;

    const int t = threadIdx.x;
    const int mbase = (blockIdx.x / 48) * 64;
    const int nbase = (blockIdx.x % 48) * 64;
    const int wv = t >> 6, lane = t & 63;
    const int quad = lane >> 4, l16 = lane & 15;

    floatx4 acc[4];
    for (int i = 0; i < 4; i++)
        for (int r = 0; r < 4; r++) acc[i][r] = 0.f;

    const int srow = t >> 2;
    const int sc8  = (t & 3) * 8;

    for (int k0 = 0; k0 < DMODEL; k0 += 32) {
        const float* ap = x + (size_t)(mbase + srow) * DMODEL + k0 + sc8;
        const float* bp = w + (size_t)(nbase + srow) * DMODEL + k0 + sc8;
        float4 a0 = *(const float4*)ap;
        float4 a1 = *(const float4*)(ap + 4);
        float4 b0 = *(const float4*)bp;
        float4 b1 = *(const float4*)(bp + 4);
        uint4 av, bv;
        av.x = pkhi(a0.x, a0.y); av.y = pkhi(a0.z, a0.w);
        av.z = pkhi(a1.x, a1.y); av.w = pkhi(a1.z, a1.w);
        bv.x = pkhi(b0.x, b0.y); bv.y = pkhi(b0.z, b0.w);
        bv.z = pkhi(b1.x, b1.y); bv.w = pkhi(b1.z, b1.w);
        __syncthreads();                        // previous iter's LDS reads done
        *(uint4*)&As[srow * 40 + sc8] = av;     // byte off = srow*80+sc8*2, 16B-aligned
        *(uint4*)&Bs[srow * 40 + sc8] = bv;
        __syncthreads();                        // stores visible
        bf16x8 af = *(const bf16x8*)&As[(wv * 16 + l16) * 40 + quad * 8];
        for (int nt = 0; nt < 4; nt++) {
            bf16x8 bf = *(const bf16x8*)&Bs[(nt * 16 + l16) * 40 + quad * 8];
            acc[nt] = __builtin_amdgcn_mfma_f32_16x16x32_bf16(af, bf, acc[nt], 0, 0, 0);
        }
    }

    // n-tile is 64 cols => single part, single head per block
    const int part = nbase >> 10;                 // 0=q 1=k 2=v
    const int h    = (nbase & 1023) >> 6;
    const int bidx = mbase >> 11;
    const int s0   = mbase & 2047;
    const size_t bh = (size_t)bidx * NH + h;

    if (part == 2) {
        // ---- V: bias, transpose 64x64 tile in LDS, blocked coalesced store
        __syncthreads();                          // main-loop LDS reads done
        unsigned short* Vtile = smem;             // 64 x 72 shorts = 4608 <= 5120
        for (int nt = 0; nt < 4; nt++) {
            const int hd = nt * 16 + l16;
            const float bvv = bias[nbase + nt * 16 + l16];
            for (int r = 0; r < 4; r++) {
                const int sl = wv * 16 + quad * 4 + r;
                Vtile[hd * 72 + sl] = f2bf(acc[nt][r] + bvv);
            }
        }
        __syncthreads();
        const int hd = t & 63, sp = t >> 6;       // sp: 0..3 -> 16 s each
        for (int c = 0; c < 2; c++) {
            const int sl0 = sp * 16 + c * 8;
            const int sblk = (s0 + sl0) >> 3;
            short8 vv = *(const short8*)&Vtile[hd * 72 + sl0];
            *(short8*)&vb[((bh * 256 + sblk) * 64 + hd) * 8] = vv;
        }
    } else {
        for (int nt = 0; nt < 4; nt++) {
            const int hd = nt * 16 + l16;
            const float bvv = bias[nbase + nt * 16 + l16];
            for (int r = 0; r < 4; r++) {
                const int s = s0 + wv * 16 + quad * 4 + r;
                float val = acc[nt][r] + bvv;
                float other = __shfl_xor(val, 1, 64);  // RoPE pair = adjacent col
                const int i = hd >> 1;
                const float f = freqs[s * 32 + i];
                const float cc = cosf(f), sn = sinf(f);
                float outv;
                if ((hd & 1) == 0) outv = val * cc - other * sn;
                else               outv = other * sn + val * cc;
                if (part == 0) {
                    outv *= 0.125f;               // fold 1/sqrt(HD), exact
                    qb[(bh * S_LEN + s) * HD + hd] = f2bf(outv);
                } else {
                    kb[((bh * 8 + (hd >> 3)) * (size_t)S_LEN + s) * 8 + (hd & 7)] = f2bf(outv);
                }
            }
        }
    }
}

// ---------------------------------------------------------------------------
// K2: causal flash attention (R4 winner, unchanged). No-max softmax (scores
// bounded ~|q||k|/8 since RoPE is a rotation -> exp safe in fp32).
// Transposed QK; barrier-free P roundtrip; 1 barrier per tile; grid 1024.
// ---------------------------------------------------------------------------
__global__ __launch_bounds__(256, 4) void attn_kernel(
    const unsigned short* __restrict__ qb, const unsigned short* __restrict__ kb,
    const unsigned short* __restrict__ vbk, unsigned short* __restrict__ ao)
{
    __shared__ __align__(16) unsigned short Ks[8 * 512];
    __shared__ __align__(16) unsigned short Vt[8 * 512];
    __shared__ __align__(16) unsigned short Pw[4][16 * 72];

    const int t = threadIdx.x;
    const int wv = t >> 6, lane = t & 63, quad = lane >> 4, l16 = lane & 15;
    const int qt   = blockIdx.x >> 5;
    const int bhid = blockIdx.x & 31;
    const int h = bhid & 15, b = bhid >> 4;
    const size_t bh = (size_t)b * NH + h;
    const unsigned short* qg  = qb + bh * S_LEN * HD;
    const unsigned short* kgB = kb + bh * 8 * S_LEN * 8;
    const unsigned short* vgB = vbk + bh * 256 * 64 * 8;

    bf16x8 qf[2];
    {
        const unsigned short* q0 = qg + (size_t)(qt * 64 + wv * 16 + l16) * HD;
        qf[0] = *(const bf16x8*)&q0[quad * 8];
        qf[1] = *(const bf16x8*)&q0[32 + quad * 8];
    }

    bf16x8 ones;
    {
        union { short8 s; bf16x8 v; } o;
        for (int j = 0; j < 8; j++) o.s[j] = 0x3F80;
        ones = o.v;
    }

    floatx4 lfr = {0.f, 0.f, 0.f, 0.f};
    floatx4 Ofr[4];
    for (int nt = 0; nt < 4; nt++)
        for (int r = 0; r < 4; r++) Ofr[nt][r] = 0.f;

    const int ntiles = qt + 1;

    for (int kt = 0; kt < ntiles; kt++) {
        const int kbase = kt * 64;
        {
            const unsigned short* g0 = kgB + ((size_t)(2 * wv) * S_LEN + kbase + lane) * 8;
            gload_lds16(g0,             &Ks[(2 * wv) * 512]);
            gload_lds16(g0 + S_LEN * 8, &Ks[(2 * wv + 1) * 512]);
            const unsigned short* g1 = vgB + ((size_t)((kbase >> 3) + 2 * wv) * 64 + lane) * 8;
            gload_lds16(g1,          &Vt[(2 * wv) * 512]);
            gload_lds16(g1 + 64 * 8, &Vt[(2 * wv + 1) * 512]);
        }
        __syncthreads();

        float pex[4][4];
        #pragma unroll
        for (int sub = 0; sub < 4; sub++) {
            bf16x8 kf0 = *(const bf16x8*)&Ks[(0 * 4 + quad) * 512 + (sub * 16 + l16) * 8];
            bf16x8 kf1 = *(const bf16x8*)&Ks[(1 * 4 + quad) * 512 + (sub * 16 + l16) * 8];
            floatx4 sacc = {0.f, 0.f, 0.f, 0.f};
            sacc = __builtin_amdgcn_mfma_f32_16x16x32_bf16(kf0, qf[0], sacc, 0, 0, 0);
            sacc = __builtin_amdgcn_mfma_f32_16x16x32_bf16(kf1, qf[1], sacc, 0, 0, 0);
            #pragma unroll
            for (int r = 0; r < 4; r++) pex[sub][r] = sacc[r];
        }
        if (kt == qt) {
            const int q = qt * 64 + wv * 16 + l16;
            #pragma unroll
            for (int sub = 0; sub < 4; sub++)
                #pragma unroll
                for (int r = 0; r < 4; r++) {
                    const int key = kbase + sub * 16 + quad * 4 + r;
                    if (key > q) pex[sub][r] = -1e30f;
                }
        }
        #pragma unroll
        for (int sub = 0; sub < 4; sub++) {
            union { unsigned short s[4]; uint2 u; } pk;
            #pragma unroll
            for (int r = 0; r < 4; r++) pk.s[r] = f2bf(__expf(pex[sub][r]));
            *(uint2*)&Pw[wv][l16 * 72 + sub * 16 + quad * 4] = pk.u;
        }
        bf16x8 pf0 = *(const bf16x8*)&Pw[wv][l16 * 72 + quad * 8];
        bf16x8 pf1 = *(const bf16x8*)&Pw[wv][l16 * 72 + 32 + quad * 8];
        lfr = __builtin_amdgcn_mfma_f32_16x16x32_bf16(ones, pf0, lfr, 0, 0, 0);
        lfr = __builtin_amdgcn_mfma_f32_16x16x32_bf16(ones, pf1, lfr, 0, 0, 0);
        #pragma unroll
        for (int nt = 0; nt < 4; nt++) {
            bf16x8 v0 = *(const bf16x8*)&Vt[(0 * 4 + quad) * 512 + (nt * 16 + l16) * 8];
            bf16x8 v1 = *(const bf16x8*)&Vt[(1 * 4 + quad) * 512 + (nt * 16 + l16) * 8];
            Ofr[nt] = __builtin_amdgcn_mfma_f32_16x16x32_bf16(pf0, v0, Ofr[nt], 0, 0, 0);
            Ofr[nt] = __builtin_amdgcn_mfma_f32_16x16x32_bf16(pf1, v1, Ofr[nt], 0, 0, 0);
        }
        __syncthreads();
    }

    float linv[4];
    #pragma unroll
    for (int r = 0; r < 4; r++) {
        float lq = __shfl(lfr[0], (lane & 48) | (quad * 4 + r), 64);
        linv[r] = 1.f / lq;
    }
    #pragma unroll
    for (int nt = 0; nt < 4; nt++)
        #pragma unroll
        for (int r = 0; r < 4; r++) {
            const int s = qt * 64 + wv * 16 + quad * 4 + r;
            ao[((size_t)b * S_LEN + s) * DMODEL + h * HD + nt * 16 + l16] =
                f2bf(Ofr[nt][r] * linv[r]);
        }
}

// ---------------------------------------------------------------------------
// K3: out = ao @ w_proj^T + b_proj.  M=4096, N=1024, K=1024. fp32 out.
// (R4 structure; B-staging conversion via v_perm truncation)
// ---------------------------------------------------------------------------
__global__ __launch_bounds__(256) void proj_kernel(
    const unsigned short* __restrict__ a, const float* __restrict__ w,
    const float* __restrict__ bias, float* __restrict__ out)
{
    __shared__ __align__(16) unsigned short As[64 * 40];
    __shared__ __align__(16) unsigned short Bs[64 * 40];
    const int t = threadIdx.x;
    const int mbase = (blockIdx.x >> 4) * 64;
    const int nbase = (blockIdx.x & 15) * 64;
    const int wv = t >> 6, lane = t & 63, quad = lane >> 4, l16 = lane & 15;

    floatx4 acc[4];
    for (int i = 0; i < 4; i++)
        for (int r = 0; r < 4; r++) acc[i][r] = 0.f;

    const int srow = t >> 2, sc8 = (t & 3) * 8;

    for (int k0 = 0; k0 < DMODEL; k0 += 32) {
        short8 av = *(const short8*)&a[(size_t)(mbase + srow) * DMODEL + k0 + sc8];
        const float* bp = w + (size_t)(nbase + srow) * DMODEL + k0 + sc8;
        float4 b0 = *(const float4*)bp;
        float4 b1 = *(const float4*)(bp + 4);
        uint4 bv;
        bv.x = pkhi(b0.x, b0.y); bv.y = pkhi(b0.z, b0.w);
        bv.z = pkhi(b1.x, b1.y); bv.w = pkhi(b1.z, b1.w);
        __syncthreads();
        *(short8*)&As[srow * 40 + sc8] = av;
        *(uint4*)&Bs[srow * 40 + sc8] = bv;
        __syncthreads();
        bf16x8 af = *(const bf16x8*)&As[(wv * 16 + l16) * 40 + quad * 8];
        for (int nt = 0; nt < 4; nt++) {
            bf16x8 bf = *(const bf16x8*)&Bs[(nt * 16 + l16) * 40 + quad * 8];
            acc[nt] = __builtin_amdgcn_mfma_f32_16x16x32_bf16(af, bf, acc[nt], 0, 0, 0);
        }
    }

    for (int nt = 0; nt < 4; nt++) {
        const int n = nbase + nt * 16 + l16;
        const float bvv = bias[n];
        for (int r = 0; r < 4; r++) {
            const int m = mbase + wv * 16 + quad * 4 + r;
            out[(size_t)m * DMODEL + n] = acc[nt][r] + bvv;
        }
    }
}

extern "C" void kernel_launch(void* const* d_in, const int* in_sizes, int n_in,
                              void* d_out, int out_size, void* d_ws, size_t ws_size,
                              hipStream_t stream) {
    const float* x      = (const float*)d_in[0];
    const float* freqs  = (const float*)d_in[2];
    const float* w_qkv  = (const float*)d_in[3];
    const float* b_qkv  = (const float*)d_in[4];
    const float* w_proj = (const float*)d_in[5];
    const float* b_proj = (const float*)d_in[6];
    float* out = (float*)d_out;

    unsigned short* ws = (unsigned short*)d_ws;
    const size_t HSZ = (size_t)2 * NH * S_LEN * HD;
    unsigned short* qb = ws;
    unsigned short* kb = ws + HSZ;
    unsigned short* vb = ws + 2 * HSZ;
    unsigned short* ao = ws + 3 * HSZ;

    qkv_rope_kernel<<<3072, 256, 0, stream>>>(x, w_qkv, b_qkv, freqs, qb, kb, vb);
    attn_kernel<<<1024, 256, 0, stream>>>(qb, kb, vb, ao);
    proj_kernel<<<1024, 256, 0, stream>>>(ao, w_proj, b_proj, out);
}

// Round 7
// 243.684 us; speedup vs baseline: 1.9259x; 1.0987x over previous
//
#include <hip/hip_runtime.h>

// Problem constants: B=2, S=2048, D=1024, H=16, HD=64
#define S_LEN 2048
#define NH 16
#define HD 64
#define DMODEL 1024

typedef __bf16 bf16x8 __attribute__((ext_vector_type(8)));
typedef float floatx4 __attribute__((ext_vector_type(4)));
typedef short short8 __attribute__((ext_vector_type(8)));

__device__ inline unsigned short f2bf(float f) {
    union { float f; unsigned u; } v; v.f = f;
    unsigned u = v.u;
    unsigned r = (u + 0x7FFFu + ((u >> 16) & 1u)) >> 16;  // RNE
    return (unsigned short)r;
}

// pack two fp32 -> bf16x2 by truncation: one v_perm_b32.
__device__ __forceinline__ unsigned pkhi(float lo, float hi) {
    union { float f; unsigned u; } a, b;
    a.f = lo; b.f = hi;
    return __builtin_amdgcn_perm(b.u, a.u, 0x07060302u);
}

__device__ __forceinline__ void gload_lds16(const void* g, void* l) {
    __builtin_amdgcn_global_load_lds(
        (const __attribute__((address_space(1))) unsigned int*)g,
        (__attribute__((address_space(3))) unsigned int*)l, 16, 0, 0);
}

// Swizzled blocked LDS layout for a 64x32 bf16 tile:
//   storage block (16B unit) = kchunk*64 + (row ^ (kchunk<<2)), kchunk = col/8.
// Bank enumeration: staging writes and b128 frag reads are both exactly 2-way
// per 16-lane phase -> conflict-free (m136: 2-way is free).
#define SWZ(kch, row) (((kch) * 64 + ((row) ^ ((kch) << 2))) * 8)

// ---------------------------------------------------------------------------
// K1: qkv = x @ w_qkv^T + b_qkv, fused RoPE + scatter.
// 64x64 tile, BK=32; register-prefetch double buffering of the fp32 loads;
// swizzled blocked LDS (conflict-free).
//  q -> [bh][s][hd] row-major, PRE-SCALED by 1/sqrt(HD)=0.125 (exact)
//  k -> blocked [bh][hdblk(8)][s(2048)][8]   (RoPE applied)
//  v -> blocked [bh][sblk(256)][hd(64)][8]   (transposed via LDS tile)
// ---------------------------------------------------------------------------
__global__ __launch_bounds__(256) void qkv_rope_kernel(
    const float* __restrict__ x, const float* __restrict__ w,
    const float* __restrict__ bias, const float* __restrict__ freqs,
    unsigned short* __restrict__ qb, unsigned short* __restrict__ kb,
    unsigned short* __restrict__ vb)
{
    __shared__ __align__(16) unsigned short smem[5120];  // As(2048)+Bs(2048); Vtile(4608) in epilogue
    unsigned short* As = smem;
    unsigned short* Bs = smem + 2048;

    const int t = threadIdx.x;
    const int mbase = (blockIdx.x / 48) * 64;
    const int nbase = (blockIdx.x % 48) * 64;
    const int wv = t >> 6, lane = t & 63;
    const int quad = lane >> 4, l16 = lane & 15;

    floatx4 acc[4];
    for (int i = 0; i < 4; i++)
        for (int r = 0; r < 4; r++) acc[i][r] = 0.f;

    const int srow = t >> 2;        // 0..63
    const int kch  = t & 3;
    const int sc8  = kch * 8;

    const int woff  = SWZ(kch, srow);
    const int aroff = SWZ(quad, wv * 16 + l16);
    int broff[4];
    #pragma unroll
    for (int nt = 0; nt < 4; nt++) broff[nt] = SWZ(quad, nt * 16 + l16);

    const float* ap = x + (size_t)(mbase + srow) * DMODEL + sc8;
    const float* bp = w + (size_t)(nbase + srow) * DMODEL + sc8;
    float4 a0 = *(const float4*)ap;
    float4 a1 = *(const float4*)(ap + 4);
    float4 b0 = *(const float4*)bp;
    float4 b1 = *(const float4*)(bp + 4);

    for (int k0 = 0; k0 < DMODEL; k0 += 32) {
        uint4 av, bv;
        av.x = pkhi(a0.x, a0.y); av.y = pkhi(a0.z, a0.w);
        av.z = pkhi(a1.x, a1.y); av.w = pkhi(a1.z, a1.w);
        bv.x = pkhi(b0.x, b0.y); bv.y = pkhi(b0.z, b0.w);
        bv.z = pkhi(b1.x, b1.y); bv.w = pkhi(b1.z, b1.w);
        __syncthreads();                        // prev iter's frag reads done
        *(uint4*)&As[woff] = av;
        *(uint4*)&Bs[woff] = bv;
        if (k0 + 32 < DMODEL) {                 // prefetch next K-tile (latency
            const float* ap2 = ap + k0 + 32;    // hidden behind this iter's MFMAs)
            a0 = *(const float4*)ap2;
            a1 = *(const float4*)(ap2 + 4);
            const float* bp2 = bp + k0 + 32;
            b0 = *(const float4*)bp2;
            b1 = *(const float4*)(bp2 + 4);
        }
        __syncthreads();                        // staging visible
        bf16x8 af = *(const bf16x8*)&As[aroff];
        #pragma unroll
        for (int nt = 0; nt < 4; nt++) {
            bf16x8 bf = *(const bf16x8*)&Bs[broff[nt]];
            acc[nt] = __builtin_amdgcn_mfma_f32_16x16x32_bf16(af, bf, acc[nt], 0, 0, 0);
        }
    }

    // n-tile is 64 cols => single part, single head per block
    const int part = nbase >> 10;                 // 0=q 1=k 2=v
    const int h    = (nbase & 1023) >> 6;
    const int bidx = mbase >> 11;
    const int s0   = mbase & 2047;
    const size_t bh = (size_t)bidx * NH + h;

    if (part == 2) {
        // ---- V: bias, transpose 64x64 tile in LDS, blocked coalesced store
        __syncthreads();                          // main-loop LDS reads done
        unsigned short* Vtile = smem;             // 64 x 72 shorts = 4608 <= 5120
        for (int nt = 0; nt < 4; nt++) {
            const int hd = nt * 16 + l16;
            const float bvv = bias[nbase + nt * 16 + l16];
            for (int r = 0; r < 4; r++) {
                const int sl = wv * 16 + quad * 4 + r;
                Vtile[hd * 72 + sl] = f2bf(acc[nt][r] + bvv);
            }
        }
        __syncthreads();
        const int hd = t & 63, sp = t >> 6;       // sp: 0..3 -> 16 s each
        for (int c = 0; c < 2; c++) {
            const int sl0 = sp * 16 + c * 8;
            const int sblk = (s0 + sl0) >> 3;
            short8 vv = *(const short8*)&Vtile[hd * 72 + sl0];
            *(short8*)&vb[((bh * 256 + sblk) * 64 + hd) * 8] = vv;
        }
    } else {
        for (int nt = 0; nt < 4; nt++) {
            const int hd = nt * 16 + l16;
            const float bvv = bias[nbase + nt * 16 + l16];
            for (int r = 0; r < 4; r++) {
                const int s = s0 + wv * 16 + quad * 4 + r;
                float val = acc[nt][r] + bvv;
                float other = __shfl_xor(val, 1, 64);  // RoPE pair = adjacent col
                const int i = hd >> 1;
                const float f = freqs[s * 32 + i];
                const float cc = cosf(f), sn = sinf(f);
                float outv;
                if ((hd & 1) == 0) outv = val * cc - other * sn;
                else               outv = other * sn + val * cc;
                if (part == 0) {
                    outv *= 0.125f;               // fold 1/sqrt(HD), exact
                    qb[(bh * S_LEN + s) * HD + hd] = f2bf(outv);
                } else {
                    kb[((bh * 8 + (hd >> 3)) * (size_t)S_LEN + s) * 8 + (hd & 7)] = f2bf(outv);
                }
            }
        }
    }
}

// ---------------------------------------------------------------------------
// K2: causal flash attention (R4/R6 winner, unchanged). No-max softmax;
// transposed QK; barrier-free P roundtrip; 1 barrier per tile; grid 1024.
// ---------------------------------------------------------------------------
__global__ __launch_bounds__(256, 4) void attn_kernel(
    const unsigned short* __restrict__ qb, const unsigned short* __restrict__ kb,
    const unsigned short* __restrict__ vbk, unsigned short* __restrict__ ao)
{
    __shared__ __align__(16) unsigned short Ks[8 * 512];
    __shared__ __align__(16) unsigned short Vt[8 * 512];
    __shared__ __align__(16) unsigned short Pw[4][16 * 72];

    const int t = threadIdx.x;
    const int wv = t >> 6, lane = t & 63, quad = lane >> 4, l16 = lane & 15;
    const int qt   = blockIdx.x >> 5;
    const int bhid = blockIdx.x & 31;
    const int h = bhid & 15, b = bhid >> 4;
    const size_t bh = (size_t)b * NH + h;
    const unsigned short* qg  = qb + bh * S_LEN * HD;
    const unsigned short* kgB = kb + bh * 8 * S_LEN * 8;
    const unsigned short* vgB = vbk + bh * 256 * 64 * 8;

    bf16x8 qf[2];
    {
        const unsigned short* q0 = qg + (size_t)(qt * 64 + wv * 16 + l16) * HD;
        qf[0] = *(const bf16x8*)&q0[quad * 8];
        qf[1] = *(const bf16x8*)&q0[32 + quad * 8];
    }

    bf16x8 ones;
    {
        union { short8 s; bf16x8 v; } o;
        for (int j = 0; j < 8; j++) o.s[j] = 0x3F80;
        ones = o.v;
    }

    floatx4 lfr = {0.f, 0.f, 0.f, 0.f};
    floatx4 Ofr[4];
    for (int nt = 0; nt < 4; nt++)
        for (int r = 0; r < 4; r++) Ofr[nt][r] = 0.f;

    const int ntiles = qt + 1;

    for (int kt = 0; kt < ntiles; kt++) {
        const int kbase = kt * 64;
        {
            const unsigned short* g0 = kgB + ((size_t)(2 * wv) * S_LEN + kbase + lane) * 8;
            gload_lds16(g0,             &Ks[(2 * wv) * 512]);
            gload_lds16(g0 + S_LEN * 8, &Ks[(2 * wv + 1) * 512]);
            const unsigned short* g1 = vgB + ((size_t)((kbase >> 3) + 2 * wv) * 64 + lane) * 8;
            gload_lds16(g1,          &Vt[(2 * wv) * 512]);
            gload_lds16(g1 + 64 * 8, &Vt[(2 * wv + 1) * 512]);
        }
        __syncthreads();

        float pex[4][4];
        #pragma unroll
        for (int sub = 0; sub < 4; sub++) {
            bf16x8 kf0 = *(const bf16x8*)&Ks[(0 * 4 + quad) * 512 + (sub * 16 + l16) * 8];
            bf16x8 kf1 = *(const bf16x8*)&Ks[(1 * 4 + quad) * 512 + (sub * 16 + l16) * 8];
            floatx4 sacc = {0.f, 0.f, 0.f, 0.f};
            sacc = __builtin_amdgcn_mfma_f32_16x16x32_bf16(kf0, qf[0], sacc, 0, 0, 0);
            sacc = __builtin_amdgcn_mfma_f32_16x16x32_bf16(kf1, qf[1], sacc, 0, 0, 0);
            #pragma unroll
            for (int r = 0; r < 4; r++) pex[sub][r] = sacc[r];
        }
        if (kt == qt) {
            const int q = qt * 64 + wv * 16 + l16;
            #pragma unroll
            for (int sub = 0; sub < 4; sub++)
                #pragma unroll
                for (int r = 0; r < 4; r++) {
                    const int key = kbase + sub * 16 + quad * 4 + r;
                    if (key > q) pex[sub][r] = -1e30f;
                }
        }
        #pragma unroll
        for (int sub = 0; sub < 4; sub++) {
            union { unsigned short s[4]; uint2 u; } pk;
            #pragma unroll
            for (int r = 0; r < 4; r++) pk.s[r] = f2bf(__expf(pex[sub][r]));
            *(uint2*)&Pw[wv][l16 * 72 + sub * 16 + quad * 4] = pk.u;
        }
        bf16x8 pf0 = *(const bf16x8*)&Pw[wv][l16 * 72 + quad * 8];
        bf16x8 pf1 = *(const bf16x8*)&Pw[wv][l16 * 72 + 32 + quad * 8];
        lfr = __builtin_amdgcn_mfma_f32_16x16x32_bf16(ones, pf0, lfr, 0, 0, 0);
        lfr = __builtin_amdgcn_mfma_f32_16x16x32_bf16(ones, pf1, lfr, 0, 0, 0);
        #pragma unroll
        for (int nt = 0; nt < 4; nt++) {
            bf16x8 v0 = *(const bf16x8*)&Vt[(0 * 4 + quad) * 512 + (nt * 16 + l16) * 8];
            bf16x8 v1 = *(const bf16x8*)&Vt[(1 * 4 + quad) * 512 + (nt * 16 + l16) * 8];
            Ofr[nt] = __builtin_amdgcn_mfma_f32_16x16x32_bf16(pf0, v0, Ofr[nt], 0, 0, 0);
            Ofr[nt] = __builtin_amdgcn_mfma_f32_16x16x32_bf16(pf1, v1, Ofr[nt], 0, 0, 0);
        }
        __syncthreads();
    }

    float linv[4];
    #pragma unroll
    for (int r = 0; r < 4; r++) {
        float lq = __shfl(lfr[0], (lane & 48) | (quad * 4 + r), 64);
        linv[r] = 1.f / lq;
    }
    #pragma unroll
    for (int nt = 0; nt < 4; nt++)
        #pragma unroll
        for (int r = 0; r < 4; r++) {
            const int s = qt * 64 + wv * 16 + quad * 4 + r;
            ao[((size_t)b * S_LEN + s) * DMODEL + h * HD + nt * 16 + l16] =
                f2bf(Ofr[nt][r] * linv[r]);
        }
}

// ---------------------------------------------------------------------------
// K3: out = ao @ w_proj^T + b_proj.  M=4096, N=1024, K=1024. fp32 out.
// Register-prefetch double buffering + swizzled conflict-free LDS.
// ---------------------------------------------------------------------------
__global__ __launch_bounds__(256) void proj_kernel(
    const unsigned short* __restrict__ a, const float* __restrict__ w,
    const float* __restrict__ bias, float* __restrict__ out)
{
    __shared__ __align__(16) unsigned short As[2048];
    __shared__ __align__(16) unsigned short Bs[2048];
    const int t = threadIdx.x;
    const int mbase = (blockIdx.x >> 4) * 64;
    const int nbase = (blockIdx.x & 15) * 64;
    const int wv = t >> 6, lane = t & 63, quad = lane >> 4, l16 = lane & 15;

    floatx4 acc[4];
    for (int i = 0; i < 4; i++)
        for (int r = 0; r < 4; r++) acc[i][r] = 0.f;

    const int srow = t >> 2;
    const int kch  = t & 3;
    const int sc8  = kch * 8;

    const int woff  = SWZ(kch, srow);
    const int aroff = SWZ(quad, wv * 16 + l16);
    int broff[4];
    #pragma unroll
    for (int nt = 0; nt < 4; nt++) broff[nt] = SWZ(quad, nt * 16 + l16);

    const unsigned short* apg = a + (size_t)(mbase + srow) * DMODEL + sc8;
    const float* bpg = w + (size_t)(nbase + srow) * DMODEL + sc8;
    short8 av8 = *(const short8*)apg;
    float4 b0 = *(const float4*)bpg;
    float4 b1 = *(const float4*)(bpg + 4);

    for (int k0 = 0; k0 < DMODEL; k0 += 32) {
        uint4 bv;
        bv.x = pkhi(b0.x, b0.y); bv.y = pkhi(b0.z, b0.w);
        bv.z = pkhi(b1.x, b1.y); bv.w = pkhi(b1.z, b1.w);
        short8 avc = av8;
        __syncthreads();
        *(short8*)&As[woff] = avc;
        *(uint4*)&Bs[woff] = bv;
        if (k0 + 32 < DMODEL) {
            av8 = *(const short8*)(apg + k0 + 32);
            const float* bp2 = bpg + k0 + 32;
            b0 = *(const float4*)bp2;
            b1 = *(const float4*)(bp2 + 4);
        }
        __syncthreads();
        bf16x8 af = *(const bf16x8*)&As[aroff];
        #pragma unroll
        for (int nt = 0; nt < 4; nt++) {
            bf16x8 bf = *(const bf16x8*)&Bs[broff[nt]];
            acc[nt] = __builtin_amdgcn_mfma_f32_16x16x32_bf16(af, bf, acc[nt], 0, 0, 0);
        }
    }

    for (int nt = 0; nt < 4; nt++) {
        const int n = nbase + nt * 16 + l16;
        const float bvv = bias[n];
        for (int r = 0; r < 4; r++) {
            const int m = mbase + wv * 16 + quad * 4 + r;
            out[(size_t)m * DMODEL + n] = acc[nt][r] + bvv;
        }
    }
}

extern "C" void kernel_launch(void* const* d_in, const int* in_sizes, int n_in,
                              void* d_out, int out_size, void* d_ws, size_t ws_size,
                              hipStream_t stream) {
    const float* x      = (const float*)d_in[0];
    const float* freqs  = (const float*)d_in[2];
    const float* w_qkv  = (const float*)d_in[3];
    const float* b_qkv  = (const float*)d_in[4];
    const float* w_proj = (const float*)d_in[5];
    const float* b_proj = (const float*)d_in[6];
    float* out = (float*)d_out;

    unsigned short* ws = (unsigned short*)d_ws;
    const size_t HSZ = (size_t)2 * NH * S_LEN * HD;
    unsigned short* qb = ws;
    unsigned short* kb = ws + HSZ;
    unsigned short* vb = ws + 2 * HSZ;
    unsigned short* ao = ws + 3 * HSZ;

    qkv_rope_kernel<<<3072, 256, 0, stream>>>(x, w_qkv, b_qkv, freqs, qb, kb, vb);
    attn_kernel<<<1024, 256, 0, stream>>>(qb, kb, vb, ao);
    proj_kernel<<<1024, 256, 0, stream>>>(ao, w_proj, b_proj, out);
}